// Round 2
// baseline (48.860 us; speedup 1.0000x reference)
//
#include <hip/hip_runtime.h>

typedef _Float16 f16x8 __attribute__((ext_vector_type(8)));
typedef float f32x4 __attribute__((ext_vector_type(4)));

// ---------------- gate primitives (state: 128 amps, 2 per lane) -------------
// amp index i = (r<<6) | lane, wire w <-> bit (6-w) (wire 0 = MSB)

__device__ __forceinline__ void ry_gate(float& a0, float& a1, int w, int lane,
                                        float c, float s) {
  if (w == 0) {
    float n0 = c * a0 - s * a1;
    float n1 = s * a0 + c * a1;
    a0 = n0; a1 = n1;
  } else {
    int m = 1 << (6 - w);
    float p0 = __shfl_xor(a0, m);
    float p1 = __shfl_xor(a1, m);
    if (lane & m) {
      a0 = s * p0 + c * a0;
      a1 = s * p1 + c * a1;
    } else {
      a0 = c * a0 - s * p0;
      a1 = c * a1 - s * p1;
    }
  }
}

__device__ __forceinline__ void cnot_gate(float& a0, float& a1, int c, int t,
                                          int lane) {
  if (c == 0) {            // control = wire0 (bit6): r==1 half gets target flip
    int mt = 1 << (6 - t);
    a1 = __shfl_xor(a1, mt);
  } else if (t == 0) {     // target = wire0: swap a0<->a1 where control bit set
    int mc = 1 << (6 - c);
    if (lane & mc) { float tmp = a0; a0 = a1; a1 = tmp; }
  } else {
    int mc = 1 << (6 - c), mt = 1 << (6 - t);
    float p0 = __shfl_xor(a0, mt);
    float p1 = __shfl_xor(a1, mt);
    if (lane & mc) { a0 = p0; a1 = p1; }
  }
}

// ---------------- kernel 1: build W[n][k] = U[n][k] (f16) -------------------
__global__ __launch_bounds__(64) void basis_kernel(
    const float* __restrict__ qc1, const float* __restrict__ qc2,
    const float* __restrict__ qc3, const float* __restrict__ qc4,
    const float* __restrict__ qc5, const float* __restrict__ qc6,
    const float* __restrict__ qp1, const float* __restrict__ qp2,
    const float* __restrict__ qp3, const float* __restrict__ qp4,
    const float* __restrict__ qp5, const float* __restrict__ qp6,
    const float* __restrict__ qf, _Float16* __restrict__ wt) {
  __shared__ float2 cs[208];
  int lane = threadIdx.x;

  // angles laid out flat: [QC1,QP1,QC2,QP2,...,QC6,QP6,QF] -> (cos,sin)(a/2)
  {
    const float* arrs[13] = {qc1, qp1, qc2, qp2, qc3, qp3, qc4,
                             qp4, qc5, qp5, qc6, qp6, qf};
    const int sizes[13] = {42, 12, 36, 10, 30, 8, 24, 6, 18, 4, 12, 2, 1};
    for (int t = lane; t < 205; t += 64) {
      int base = 0; float ang = 0.f;
#pragma unroll
      for (int s2 = 0; s2 < 13; ++s2) {
        if (t >= base && t < base + sizes[s2]) ang = arrs[s2][t - base];
        base += sizes[s2];
      }
      float h = 0.5f * ang;
      cs[t] = make_float2(cosf(h), sinf(h));
    }
  }
  __syncthreads();

  int k = blockIdx.x;  // basis column
  float a0 = ((k >> 6) == 0 && (k & 63) == lane) ? 1.0f : 0.0f;
  float a1 = ((k >> 6) == 1 && (k & 63) == lane) ? 1.0f : 0.0f;
  int g = 0;

  const int qcstep[6] = {4, 1, 2, 1, 1, 1};
#define RYG(w)                                        \
  { float2 csv = cs[g++]; ry_gate(a0, a1, (w), lane, csv.x, csv.y); }
#define CNG(c, t) cnot_gate(a0, a1, (c), (t), lane);

#pragma unroll
  for (int j = 0; j < 6; ++j) {
    int sq = 7 - j;
    int step = qcstep[j];
    for (int i = 0; i < sq; ++i) { RYG(i); }
    for (int i = 0; i < sq; ++i) {
      if (i == 0) { RYG(0); CNG(sq - 1, 0); RYG(0); }
      else { int w = sq - i; RYG(w); CNG(w - 1, w); RYG(w); }
    }
    for (int i = 0; i < sq; ++i) { RYG(i); }
    int control = 0, controled = step;
    for (int i = 0; i < sq; ++i) {
      RYG(controled); CNG(control, controled); RYG(controled);
      control = controled; controled = (controled + step) % sq;
    }
    for (int i = 0; i < sq - 1; ++i) { RYG(i + 1); CNG(i, i + 1); RYG(i + 1); }
  }
  RYG(0);  // final QF rotation (index 204)

  wt[lane * 128 + k] = (_Float16)a0;
  wt[(lane + 64) * 128 + k] = (_Float16)a1;
#undef RYG
#undef CNG
}

// ---------------- kernel 2: Z = X * W^T, out = row-half prob ----------------
// mfma_f32_16x16x32_f16: A lane l holds A[l&15][(l>>4)*8 + j]
//                        B lane l holds B[(l>>4)*8 + j][l&15]  (= Wt[l&15][k..])
//                        D lane l holds D[(l>>4)*4 + r][l&15]
__global__ __launch_bounds__(256) void qcnn_gemm(const float* __restrict__ X,
                                                 const _Float16* __restrict__ wt,
                                                 float* __restrict__ out,
                                                 int M) {
  __shared__ uint4 ldsbuf[2048];  // 32 KB: Wt[128][128] f16, XOR-swizzled rows
  char* lds = (char*)ldsbuf;
  int tid = threadIdx.x;

  // stage Wt -> LDS with byte ^= ((row&7)<<4) swizzle (conflict-free b128 read)
#pragma unroll
  for (int it = 0; it < 8; ++it) {
    int idx16 = it * 2048 + tid * 8;
    int n = idx16 >> 7;
    int k2 = (idx16 & 127) * 2;  // byte offset within row
    uint4 v = *(const uint4*)(wt + idx16);
    *(uint4*)(lds + n * 256 + (k2 ^ ((n & 7) << 4))) = v;
  }
  __syncthreads();

  int wave = tid >> 6, lane = tid & 63;
  int rb = blockIdx.x * 128 + wave * 32;
  if (rb >= M) return;
  int lr = lane & 15;
  int lk = (lane >> 4) * 8;
  const float* xp = X + (size_t)(rb + lr) * 128 + lk;

  // load 32 rows x 128 K of X, convert to f16 A-fragments
  f16x8 a[2][4];
#pragma unroll
  for (int mt = 0; mt < 2; ++mt) {
#pragma unroll
    for (int ks = 0; ks < 4; ++ks) {
      const float* p = xp + mt * 16 * 128 + ks * 32;
      float4 v0 = *(const float4*)p;
      float4 v1 = *(const float4*)(p + 4);
      f16x8 f;
      f[0] = (_Float16)v0.x; f[1] = (_Float16)v0.y;
      f[2] = (_Float16)v0.z; f[3] = (_Float16)v0.w;
      f[4] = (_Float16)v1.x; f[5] = (_Float16)v1.y;
      f[6] = (_Float16)v1.z; f[7] = (_Float16)v1.w;
      a[mt][ks] = f;
    }
  }

  f32x4 acc[2][8];
#pragma unroll
  for (int mt = 0; mt < 2; ++mt)
#pragma unroll
    for (int nf = 0; nf < 8; ++nf) acc[mt][nf] = (f32x4){0.f, 0.f, 0.f, 0.f};

  int swz = (lane & 7) << 4;
#pragma unroll
  for (int ks = 0; ks < 4; ++ks) {
#pragma unroll
    for (int nf = 0; nf < 8; ++nf) {
      int n = nf * 16 + lr;
      int boff = (ks * 64 + lk * 2) ^ swz;
      f16x8 b = *(const f16x8*)(lds + n * 256 + boff);
      acc[0][nf] = __builtin_amdgcn_mfma_f32_16x16x32_f16(a[0][ks], b, acc[0][nf], 0, 0, 0);
      acc[1][nf] = __builtin_amdgcn_mfma_f32_16x16x32_f16(a[1][ks], b, acc[1][nf], 0, 0, 0);
    }
  }

  // epilogue: s0 = sum_{n<64} z^2, s1 = sum_{n>=64} z^2 per row; out = [s0,s1]/(s0+s1)
#pragma unroll
  for (int mt = 0; mt < 2; ++mt) {
    float s0[4], s1[4];
#pragma unroll
    for (int r = 0; r < 4; ++r) {
      float t0 = 0.f, t1 = 0.f;
#pragma unroll
      for (int nf = 0; nf < 4; ++nf) t0 += acc[mt][nf][r] * acc[mt][nf][r];
#pragma unroll
      for (int nf = 4; nf < 8; ++nf) t1 += acc[mt][nf][r] * acc[mt][nf][r];
      s0[r] = t0; s1[r] = t1;
    }
#pragma unroll
    for (int d = 1; d < 16; d <<= 1) {
#pragma unroll
      for (int r = 0; r < 4; ++r) {
        s0[r] += __shfl_xor(s0[r], d);
        s1[r] += __shfl_xor(s1[r], d);
      }
    }
    int grp = lane >> 4;
    int row = rb + mt * 16 + grp * 4;
#pragma unroll
    for (int r = 0; r < 4; ++r) {
      if ((lane & 15) == r) {
        float inv = 1.0f / (s0[r] + s1[r]);
        *(float2*)(out + (size_t)(row + r) * 2) =
            make_float2(s0[r] * inv, s1[r] * inv);
      }
    }
  }
}

// ---------------------------------------------------------------------------
extern "C" void kernel_launch(void* const* d_in, const int* in_sizes, int n_in,
                              void* d_out, int out_size, void* d_ws,
                              size_t ws_size, hipStream_t stream) {
  const float* X = (const float*)d_in[0];
  _Float16* wt = (_Float16*)d_ws;  // 128*128 f16 = 32 KB

  // setup_inputs() dict order is INTERLEAVED: x, QC1, QP1, QC2, QP2, ...,
  // QC6, QP6, QF  (QC{j+1} and QP{j+1} inserted in the same loop iteration).
  basis_kernel<<<128, 64, 0, stream>>>(
      /*qc1*/ (const float*)d_in[1], /*qc2*/ (const float*)d_in[3],
      /*qc3*/ (const float*)d_in[5], /*qc4*/ (const float*)d_in[7],
      /*qc5*/ (const float*)d_in[9], /*qc6*/ (const float*)d_in[11],
      /*qp1*/ (const float*)d_in[2], /*qp2*/ (const float*)d_in[4],
      /*qp3*/ (const float*)d_in[6], /*qp4*/ (const float*)d_in[8],
      /*qp5*/ (const float*)d_in[10], /*qp6*/ (const float*)d_in[12],
      /*qf*/ (const float*)d_in[13], wt);

  int M = in_sizes[0] / 128;  // 262144
  qcnn_gemm<<<(M + 127) / 128, 256, 0, stream>>>(X, wt, (float*)d_out, M);
}

// Round 3
// 43.219 us; speedup vs baseline: 1.1305x; 1.1305x over previous
//
#include <hip/hip_runtime.h>

typedef _Float16 f16x8 __attribute__((ext_vector_type(8)));
typedef float f32x4 __attribute__((ext_vector_type(4)));

// ---------------- gate primitives (state: 128 amps, 2 per lane) -------------
// amp index i = (r<<6) | lane, wire w <-> bit (6-w) (wire 0 = MSB)

__device__ __forceinline__ void ry_gate(float& a0, float& a1, int w, int lane,
                                        float c, float s) {
  if (w == 0) {
    float n0 = c * a0 - s * a1;
    float n1 = s * a0 + c * a1;
    a0 = n0; a1 = n1;
  } else {
    int m = 1 << (6 - w);
    float p0 = __shfl_xor(a0, m);
    float p1 = __shfl_xor(a1, m);
    if (lane & m) {
      a0 = s * p0 + c * a0;
      a1 = s * p1 + c * a1;
    } else {
      a0 = c * a0 - s * p0;
      a1 = c * a1 - s * p1;
    }
  }
}

__device__ __forceinline__ void cnot_gate(float& a0, float& a1, int c, int t,
                                          int lane) {
  if (c == 0) {            // control = wire0 (bit6): r==1 half gets target flip
    int mt = 1 << (6 - t);
    a1 = __shfl_xor(a1, mt);
  } else if (t == 0) {     // target = wire0: swap a0<->a1 where control bit set
    int mc = 1 << (6 - c);
    if (lane & mc) { float tmp = a0; a0 = a1; a1 = tmp; }
  } else {
    int mc = 1 << (6 - c), mt = 1 << (6 - t);
    float p0 = __shfl_xor(a0, mt);
    float p1 = __shfl_xor(a1, mt);
    if (lane & mc) { a0 = p0; a1 = p1; }
  }
}

// ---------------- kernel 1: build W[n][k] = U[n][k] (f16) -------------------
__global__ __launch_bounds__(64) void basis_kernel(
    const float* __restrict__ qc1, const float* __restrict__ qc2,
    const float* __restrict__ qc3, const float* __restrict__ qc4,
    const float* __restrict__ qc5, const float* __restrict__ qc6,
    const float* __restrict__ qp1, const float* __restrict__ qp2,
    const float* __restrict__ qp3, const float* __restrict__ qp4,
    const float* __restrict__ qp5, const float* __restrict__ qp6,
    const float* __restrict__ qf, _Float16* __restrict__ wt) {
  __shared__ float2 cs[208];
  int lane = threadIdx.x;

  // angles laid out flat: [QC1,QP1,QC2,QP2,...,QC6,QP6,QF] -> (cos,sin)(a/2)
  {
    const float* arrs[13] = {qc1, qp1, qc2, qp2, qc3, qp3, qc4,
                             qp4, qc5, qp5, qc6, qp6, qf};
    const int sizes[13] = {42, 12, 36, 10, 30, 8, 24, 6, 18, 4, 12, 2, 1};
    for (int t = lane; t < 205; t += 64) {
      int base = 0; float ang = 0.f;
#pragma unroll
      for (int s2 = 0; s2 < 13; ++s2) {
        if (t >= base && t < base + sizes[s2]) ang = arrs[s2][t - base];
        base += sizes[s2];
      }
      float h = 0.5f * ang;
      cs[t] = make_float2(cosf(h), sinf(h));
    }
  }
  __syncthreads();

  int k = blockIdx.x;  // basis column
  float a0 = ((k >> 6) == 0 && (k & 63) == lane) ? 1.0f : 0.0f;
  float a1 = ((k >> 6) == 1 && (k & 63) == lane) ? 1.0f : 0.0f;
  int g = 0;

  const int qcstep[6] = {4, 1, 2, 1, 1, 1};
#define RYG(w)                                        \
  { float2 csv = cs[g++]; ry_gate(a0, a1, (w), lane, csv.x, csv.y); }
#define CNG(c, t) cnot_gate(a0, a1, (c), (t), lane);

#pragma unroll
  for (int j = 0; j < 6; ++j) {
    int sq = 7 - j;
    int step = qcstep[j];
    for (int i = 0; i < sq; ++i) { RYG(i); }
    for (int i = 0; i < sq; ++i) {
      if (i == 0) { RYG(0); CNG(sq - 1, 0); RYG(0); }
      else { int w = sq - i; RYG(w); CNG(w - 1, w); RYG(w); }
    }
    for (int i = 0; i < sq; ++i) { RYG(i); }
    int control = 0, controled = step;
    for (int i = 0; i < sq; ++i) {
      RYG(controled); CNG(control, controled); RYG(controled);
      control = controled; controled = (controled + step) % sq;
    }
    for (int i = 0; i < sq - 1; ++i) { RYG(i + 1); CNG(i, i + 1); RYG(i + 1); }
  }
  RYG(0);  // final QF rotation (index 204)

  wt[lane * 128 + k] = (_Float16)a0;
  wt[(lane + 64) * 128 + k] = (_Float16)a1;
#undef RYG
#undef CNG
}

// ---------------- kernel 2: Z = X * W^T, out = row-half prob ----------------
// mfma_f32_16x16x32_f16: A lane l holds A[l&15][(l>>4)*8 + j]
//                        B lane l holds B[(l>>4)*8 + j][l&15]  (= Wt[l&15][k..])
//                        D lane l holds D[(l>>4)*4 + r][l&15]
// __launch_bounds__(256, 4): cap VGPRs at 128 -> 4 waves/SIMD (16 waves/CU).
__global__ __launch_bounds__(256, 4) void qcnn_gemm(
    const float* __restrict__ X, const _Float16* __restrict__ wt,
    float* __restrict__ out, int M) {
  __shared__ uint4 ldsbuf[2048];  // 32 KB: Wt[128][128] f16, XOR-swizzled rows
  char* lds = (char*)ldsbuf;
  int tid = threadIdx.x;

  // stage Wt -> LDS with byte ^= ((row&7)<<4) swizzle (conflict-free b128 read)
#pragma unroll
  for (int it = 0; it < 8; ++it) {
    int idx16 = it * 2048 + tid * 8;
    int n = idx16 >> 7;
    int k2 = (idx16 & 127) * 2;  // byte offset within row
    uint4 v = *(const uint4*)(wt + idx16);
    *(uint4*)(lds + n * 256 + (k2 ^ ((n & 7) << 4))) = v;
  }
  __syncthreads();

  int wave = tid >> 6, lane = tid & 63;
  int rb0 = blockIdx.x * 128 + wave * 32;
  if (rb0 >= M) return;
  int lr = lane & 15;
  int lk = (lane >> 4) * 8;
  int swz = (lane & 7) << 4;
  int grp = lane >> 4;

  // two 16-row halves processed SEQUENTIALLY to keep VGPR pressure low
  for (int mt = 0; mt < 2; ++mt) {
    int rb = rb0 + mt * 16;
    const float* xp = X + (size_t)(rb + lr) * 128 + lk;

    float4 v0[4], v1[4];
#pragma unroll
    for (int ks = 0; ks < 4; ++ks) {
      v0[ks] = *(const float4*)(xp + ks * 32);
      v1[ks] = *(const float4*)(xp + ks * 32 + 4);
    }

    f32x4 acc[8];
#pragma unroll
    for (int nf = 0; nf < 8; ++nf) acc[nf] = (f32x4){0.f, 0.f, 0.f, 0.f};

#pragma unroll
    for (int ks = 0; ks < 4; ++ks) {
      f16x8 a;
      a[0] = (_Float16)v0[ks].x; a[1] = (_Float16)v0[ks].y;
      a[2] = (_Float16)v0[ks].z; a[3] = (_Float16)v0[ks].w;
      a[4] = (_Float16)v1[ks].x; a[5] = (_Float16)v1[ks].y;
      a[6] = (_Float16)v1[ks].z; a[7] = (_Float16)v1[ks].w;
      int boff = (ks * 64 + lk * 2) ^ swz;
#pragma unroll
      for (int nf = 0; nf < 8; ++nf) {
        int n = nf * 16 + lr;
        f16x8 b = *(const f16x8*)(lds + n * 256 + boff);
        acc[nf] = __builtin_amdgcn_mfma_f32_16x16x32_f16(a, b, acc[nf], 0, 0, 0);
      }
    }

    // epilogue: s0 = sum_{n<64} z^2, s1 = sum_{n>=64} z^2 per row
    float s0[4], s1[4];
#pragma unroll
    for (int r = 0; r < 4; ++r) {
      float t0 = 0.f, t1 = 0.f;
#pragma unroll
      for (int nf = 0; nf < 4; ++nf) t0 += acc[nf][r] * acc[nf][r];
#pragma unroll
      for (int nf = 4; nf < 8; ++nf) t1 += acc[nf][r] * acc[nf][r];
      s0[r] = t0; s1[r] = t1;
    }
#pragma unroll
    for (int d = 1; d < 16; d <<= 1) {
#pragma unroll
      for (int r = 0; r < 4; ++r) {
        s0[r] += __shfl_xor(s0[r], d);
        s1[r] += __shfl_xor(s1[r], d);
      }
    }
    int row = rb + grp * 4;
#pragma unroll
    for (int r = 0; r < 4; ++r) {
      if ((lane & 15) == r) {
        float inv = 1.0f / (s0[r] + s1[r]);
        *(float2*)(out + (size_t)(row + r) * 2) =
            make_float2(s0[r] * inv, s1[r] * inv);
      }
    }
  }
}

// ---------------------------------------------------------------------------
extern "C" void kernel_launch(void* const* d_in, const int* in_sizes, int n_in,
                              void* d_out, int out_size, void* d_ws,
                              size_t ws_size, hipStream_t stream) {
  const float* X = (const float*)d_in[0];
  _Float16* wt = (_Float16*)d_ws;  // 128*128 f16 = 32 KB

  // setup_inputs() dict order is INTERLEAVED: x, QC1, QP1, QC2, QP2, ...,
  // QC6, QP6, QF  (QC{j+1} and QP{j+1} inserted in the same loop iteration).
  basis_kernel<<<128, 64, 0, stream>>>(
      /*qc1*/ (const float*)d_in[1], /*qc2*/ (const float*)d_in[3],
      /*qc3*/ (const float*)d_in[5], /*qc4*/ (const float*)d_in[7],
      /*qc5*/ (const float*)d_in[9], /*qc6*/ (const float*)d_in[11],
      /*qp1*/ (const float*)d_in[2], /*qp2*/ (const float*)d_in[4],
      /*qp3*/ (const float*)d_in[6], /*qp4*/ (const float*)d_in[8],
      /*qp5*/ (const float*)d_in[10], /*qp6*/ (const float*)d_in[12],
      /*qf*/ (const float*)d_in[13], wt);

  int M = in_sizes[0] / 128;  // 262144
  qcnn_gemm<<<(M + 127) / 128, 256, 0, stream>>>(X, wt, (float*)d_out, M);
}

// Round 5
// 42.576 us; speedup vs baseline: 1.1476x; 1.0151x over previous
//
#include <hip/hip_runtime.h>

typedef _Float16 f16x8 __attribute__((ext_vector_type(8)));
typedef float f32x4 __attribute__((ext_vector_type(4)));

// ---------------- gate primitives (state: 128 amps, 2 per lane) -------------
// amp index i = (r<<6) | lane, wire w <-> bit (6-w) (wire 0 = MSB)

__device__ __forceinline__ void ry_gate(float& a0, float& a1, int w, int lane,
                                        float c, float s) {
  if (w == 0) {
    float n0 = c * a0 - s * a1;
    float n1 = s * a0 + c * a1;
    a0 = n0; a1 = n1;
  } else {
    int m = 1 << (6 - w);
    float p0 = __shfl_xor(a0, m);
    float p1 = __shfl_xor(a1, m);
    if (lane & m) {
      a0 = s * p0 + c * a0;
      a1 = s * p1 + c * a1;
    } else {
      a0 = c * a0 - s * p0;
      a1 = c * a1 - s * p1;
    }
  }
}

__device__ __forceinline__ void cnot_gate(float& a0, float& a1, int c, int t,
                                          int lane) {
  if (c == 0) {            // control = wire0 (bit6): r==1 half gets target flip
    int mt = 1 << (6 - t);
    a1 = __shfl_xor(a1, mt);
  } else if (t == 0) {     // target = wire0: swap a0<->a1 where control bit set
    int mc = 1 << (6 - c);
    if (lane & mc) { float tmp = a0; a0 = a1; a1 = tmp; }
  } else {
    int mc = 1 << (6 - c), mt = 1 << (6 - t);
    float p0 = __shfl_xor(a0, mt);
    float p1 = __shfl_xor(a1, mt);
    if (lane & mc) { a0 = p0; a1 = p1; }
  }
}

// ---------------- kernel 1: build W[n][k] = U[n][k] (f16) -------------------
__global__ __launch_bounds__(64) void basis_kernel(
    const float* __restrict__ qc1, const float* __restrict__ qc2,
    const float* __restrict__ qc3, const float* __restrict__ qc4,
    const float* __restrict__ qc5, const float* __restrict__ qc6,
    const float* __restrict__ qp1, const float* __restrict__ qp2,
    const float* __restrict__ qp3, const float* __restrict__ qp4,
    const float* __restrict__ qp5, const float* __restrict__ qp6,
    const float* __restrict__ qf, _Float16* __restrict__ wt) {
  __shared__ float2 cs[208];
  int lane = threadIdx.x;

  // angles laid out flat: [QC1,QP1,QC2,QP2,...,QC6,QP6,QF] -> (cos,sin)(a/2)
  {
    const float* arrs[13] = {qc1, qp1, qc2, qp2, qc3, qp3, qc4,
                             qp4, qc5, qp5, qc6, qp6, qf};
    const int sizes[13] = {42, 12, 36, 10, 30, 8, 24, 6, 18, 4, 12, 2, 1};
    for (int t = lane; t < 205; t += 64) {
      int base = 0; float ang = 0.f;
#pragma unroll
      for (int s2 = 0; s2 < 13; ++s2) {
        if (t >= base && t < base + sizes[s2]) ang = arrs[s2][t - base];
        base += sizes[s2];
      }
      float h = 0.5f * ang;
      cs[t] = make_float2(cosf(h), sinf(h));
    }
  }
  __syncthreads();

  int k = blockIdx.x;  // basis column
  float a0 = ((k >> 6) == 0 && (k & 63) == lane) ? 1.0f : 0.0f;
  float a1 = ((k >> 6) == 1 && (k & 63) == lane) ? 1.0f : 0.0f;
  int g = 0;

  const int qcstep[6] = {4, 1, 2, 1, 1, 1};
#define RYG(w)                                        \
  { float2 csv = cs[g++]; ry_gate(a0, a1, (w), lane, csv.x, csv.y); }
#define CNG(c, t) cnot_gate(a0, a1, (c), (t), lane);

#pragma unroll
  for (int j = 0; j < 6; ++j) {
    int sq = 7 - j;
    int step = qcstep[j];
    for (int i = 0; i < sq; ++i) { RYG(i); }
    for (int i = 0; i < sq; ++i) {
      if (i == 0) { RYG(0); CNG(sq - 1, 0); RYG(0); }
      else { int w = sq - i; RYG(w); CNG(w - 1, w); RYG(w); }
    }
    for (int i = 0; i < sq; ++i) { RYG(i); }
    int control = 0, controled = step;
    for (int i = 0; i < sq; ++i) {
      RYG(controled); CNG(control, controled); RYG(controled);
      control = controled; controled = (controled + step) % sq;
    }
    for (int i = 0; i < sq - 1; ++i) { RYG(i + 1); CNG(i, i + 1); RYG(i + 1); }
  }
  RYG(0);  // final QF rotation (index 204)

  wt[lane * 128 + k] = (_Float16)a0;
  wt[(lane + 64) * 128 + k] = (_Float16)a1;
#undef RYG
#undef CNG
}

// ---------------- kernel 2: Z = X * W^T, out = row-half prob ----------------
// mfma_f32_16x16x32_f16: A lane l holds A[l&15][(l>>4)*8 + j]
//                        B lane l holds B[(l>>4)*8 + j][l&15]  (= Wt[l&15][k..])
//                        D lane l holds D[(l>>4)*4 + r][l&15]
// Grid-stride tiles: block owns 256 rows (4 iters x 64), LDS staged once.
// Per-wave pipeline: iter t's cvt frees v-regs, then iter t+1's loads issue,
// then MFMA/epilogue of t runs while those loads are in flight.
__global__ __launch_bounds__(256, 4) void qcnn_gemm(
    const float* __restrict__ X, const _Float16* __restrict__ wt,
    float* __restrict__ out, int M) {
  __shared__ uint4 ldsbuf[2048];  // 32 KB: Wt[128][128] f16, XOR-swizzled rows
  char* lds = (char*)ldsbuf;
  int tid = threadIdx.x;
  int wave = tid >> 6, lane = tid & 63;
  int lr = lane & 15;
  int g = lane >> 4;
  int lk = g * 8;
  int swz = (lane & 7) << 4;

  size_t base0 = (size_t)blockIdx.x * 256 + wave * 16;  // this wave's row base

  // prefetch iter-0 X loads (in flight during LDS staging + barrier)
  float4 v0[4], v1[4];
  if (base0 < (size_t)M) {
    const float* xp = X + (base0 + lr) * 128 + lk;
#pragma unroll
    for (int ks = 0; ks < 4; ++ks) {
      v0[ks] = *(const float4*)(xp + ks * 32);
      v1[ks] = *(const float4*)(xp + ks * 32 + 4);
    }
  }

  // stage Wt -> LDS with byte ^= ((row&7)<<4) swizzle (conflict-free b128 read)
#pragma unroll
  for (int it = 0; it < 8; ++it) {
    int idx16 = it * 2048 + tid * 8;
    int n = idx16 >> 7;
    int k2 = (idx16 & 127) * 2;  // byte offset within row
    uint4 w = *(const uint4*)(wt + idx16);
    *(uint4*)(lds + n * 256 + (k2 ^ ((n & 7) << 4))) = w;
  }
  __syncthreads();

#pragma unroll
  for (int t = 0; t < 4; ++t) {
    size_t rb = base0 + (size_t)t * 64;
    if (rb < (size_t)M) {
      // convert current tile to f16 A-fragments (frees v0/v1)
      f16x8 a[4];
#pragma unroll
      for (int ks = 0; ks < 4; ++ks) {
        auto p0 = __builtin_amdgcn_cvt_pkrtz(v0[ks].x, v0[ks].y);
        auto p1 = __builtin_amdgcn_cvt_pkrtz(v0[ks].z, v0[ks].w);
        auto p2 = __builtin_amdgcn_cvt_pkrtz(v1[ks].x, v1[ks].y);
        auto p3 = __builtin_amdgcn_cvt_pkrtz(v1[ks].z, v1[ks].w);
        f16x8 f;
        f[0] = (_Float16)p0[0]; f[1] = (_Float16)p0[1];
        f[2] = (_Float16)p1[0]; f[3] = (_Float16)p1[1];
        f[4] = (_Float16)p2[0]; f[5] = (_Float16)p2[1];
        f[6] = (_Float16)p3[0]; f[7] = (_Float16)p3[1];
        a[ks] = f;
      }

      // issue next tile's loads early — in flight during MFMA + epilogue
      if (t < 3) {
        size_t rn = base0 + (size_t)(t + 1) * 64;
        if (rn < (size_t)M) {
          const float* xp = X + (rn + lr) * 128 + lk;
#pragma unroll
          for (int ks = 0; ks < 4; ++ks) {
            v0[ks] = *(const float4*)(xp + ks * 32);
            v1[ks] = *(const float4*)(xp + ks * 32 + 4);
          }
        }
      }

      f32x4 acc[8];
#pragma unroll
      for (int nf = 0; nf < 8; ++nf) acc[nf] = (f32x4){0.f, 0.f, 0.f, 0.f};

#pragma unroll
      for (int ks = 0; ks < 4; ++ks) {
        int boff = (ks * 64 + lk * 2) ^ swz;
#pragma unroll
        for (int nf = 0; nf < 8; ++nf) {
          f16x8 b = *(const f16x8*)(lds + (nf * 16 + lr) * 256 + boff);
          acc[nf] = __builtin_amdgcn_mfma_f32_16x16x32_f16(a[ks], b, acc[nf], 0, 0, 0);
        }
      }

      // epilogue: s0 = sum_{n<64} z^2, s1 = sum_{n>=64} z^2 per row
      float s0[4], s1[4];
#pragma unroll
      for (int r = 0; r < 4; ++r) {
        float t0 = 0.f, t1 = 0.f;
#pragma unroll
        for (int nf = 0; nf < 4; ++nf) t0 += acc[nf][r] * acc[nf][r];
#pragma unroll
        for (int nf = 4; nf < 8; ++nf) t1 += acc[nf][r] * acc[nf][r];
        s0[r] = t0; s1[r] = t1;
      }
#pragma unroll
      for (int d = 1; d < 16; d <<= 1) {  // d=1,2,4,8: within 16-lane group
#pragma unroll
        for (int r = 0; r < 4; ++r) {
          s0[r] += __shfl_xor(s0[r], d);
          s1[r] += __shfl_xor(s1[r], d);
        }
      }
      size_t row = rb + g * 4;
#pragma unroll
      for (int r = 0; r < 4; ++r) {
        if ((lane & 15) == r) {
          float inv = 1.0f / (s0[r] + s1[r]);
          *(float2*)(out + (row + r) * 2) =
              make_float2(s0[r] * inv, s1[r] * inv);
        }
      }
    }
  }
}

// ---------------------------------------------------------------------------
extern "C" void kernel_launch(void* const* d_in, const int* in_sizes, int n_in,
                              void* d_out, int out_size, void* d_ws,
                              size_t ws_size, hipStream_t stream) {
  const float* X = (const float*)d_in[0];
  _Float16* wt = (_Float16*)d_ws;  // 128*128 f16 = 32 KB

  // setup_inputs() dict order is INTERLEAVED: x, QC1, QP1, QC2, QP2, ...,
  // QC6, QP6, QF  (QC{j+1} and QP{j+1} inserted in the same loop iteration).
  basis_kernel<<<128, 64, 0, stream>>>(
      /*qc1*/ (const float*)d_in[1], /*qc2*/ (const float*)d_in[3],
      /*qc3*/ (const float*)d_in[5], /*qc4*/ (const float*)d_in[7],
      /*qc5*/ (const float*)d_in[9], /*qc6*/ (const float*)d_in[11],
      /*qp1*/ (const float*)d_in[2], /*qp2*/ (const float*)d_in[4],
      /*qp3*/ (const float*)d_in[6], /*qp4*/ (const float*)d_in[8],
      /*qp5*/ (const float*)d_in[10], /*qp6*/ (const float*)d_in[12],
      /*qf*/ (const float*)d_in[13], wt);

  int M = in_sizes[0] / 128;  // 262144
  int nblk = (M + 255) / 256;
  qcnn_gemm<<<nblk, 256, 0, stream>>>(X, wt, (float*)d_out, M);
}

// Round 6
// 42.264 us; speedup vs baseline: 1.1561x; 1.0074x over previous
//
#include <hip/hip_runtime.h>

typedef _Float16 f16x8 __attribute__((ext_vector_type(8)));
typedef float f32x4 __attribute__((ext_vector_type(4)));

// ---------------- gate primitives (state: 128 amps, 2 per lane) -------------
// amp index i = (r<<6) | lane, wire w <-> bit (6-w) (wire 0 = MSB)

__device__ __forceinline__ void ry_gate(float& a0, float& a1, int w, int lane,
                                        float c, float s) {
  if (w == 0) {
    float n0 = c * a0 - s * a1;
    float n1 = s * a0 + c * a1;
    a0 = n0; a1 = n1;
  } else {
    int m = 1 << (6 - w);
    float p0 = __shfl_xor(a0, m);
    float p1 = __shfl_xor(a1, m);
    if (lane & m) {
      a0 = s * p0 + c * a0;
      a1 = s * p1 + c * a1;
    } else {
      a0 = c * a0 - s * p0;
      a1 = c * a1 - s * p1;
    }
  }
}

__device__ __forceinline__ void cnot_gate(float& a0, float& a1, int c, int t,
                                          int lane) {
  if (c == 0) {            // control = wire0 (bit6): r==1 half gets target flip
    int mt = 1 << (6 - t);
    a1 = __shfl_xor(a1, mt);
  } else if (t == 0) {     // target = wire0: swap a0<->a1 where control bit set
    int mc = 1 << (6 - c);
    if (lane & mc) { float tmp = a0; a0 = a1; a1 = tmp; }
  } else {
    int mc = 1 << (6 - c), mt = 1 << (6 - t);
    float p0 = __shfl_xor(a0, mt);
    float p1 = __shfl_xor(a1, mt);
    if (lane & mc) { a0 = p0; a1 = p1; }
  }
}

// ------- kernel 1: build U, store in MFMA B-FRAGMENT order (f16) -----------
// frag layout: block (ks,nf) = 1024 B at (ks*8+nf)*1024; lane l's 16 B at
// +l*16 holds U[n = nf*16 + (l&15)][k = ks*32 + (l>>4)*8 + j], j=0..7.
// => element (n,k): ks=k>>5, khi=(k>>3)&3, j=k&7, nf=n>>4, lr=n&15
//    f16 index = (ks*8+nf)*512 + khi*128 + lr*8 + j
__global__ __launch_bounds__(64) void basis_kernel(
    const float* __restrict__ qc1, const float* __restrict__ qc2,
    const float* __restrict__ qc3, const float* __restrict__ qc4,
    const float* __restrict__ qc5, const float* __restrict__ qc6,
    const float* __restrict__ qp1, const float* __restrict__ qp2,
    const float* __restrict__ qp3, const float* __restrict__ qp4,
    const float* __restrict__ qp5, const float* __restrict__ qp6,
    const float* __restrict__ qf, _Float16* __restrict__ wt) {
  __shared__ float2 cs[208];
  int lane = threadIdx.x;

  // angles laid out flat: [QC1,QP1,QC2,QP2,...,QC6,QP6,QF] -> (cos,sin)(a/2)
  {
    const float* arrs[13] = {qc1, qp1, qc2, qp2, qc3, qp3, qc4,
                             qp4, qc5, qp5, qc6, qp6, qf};
    const int sizes[13] = {42, 12, 36, 10, 30, 8, 24, 6, 18, 4, 12, 2, 1};
    for (int t = lane; t < 205; t += 64) {
      int base = 0; float ang = 0.f;
#pragma unroll
      for (int s2 = 0; s2 < 13; ++s2) {
        if (t >= base && t < base + sizes[s2]) ang = arrs[s2][t - base];
        base += sizes[s2];
      }
      float h = 0.5f * ang;
      cs[t] = make_float2(cosf(h), sinf(h));
    }
  }
  __syncthreads();

  int k = blockIdx.x;  // basis column
  float a0 = ((k >> 6) == 0 && (k & 63) == lane) ? 1.0f : 0.0f;
  float a1 = ((k >> 6) == 1 && (k & 63) == lane) ? 1.0f : 0.0f;
  int g = 0;

  const int qcstep[6] = {4, 1, 2, 1, 1, 1};
#define RYG(w)                                        \
  { float2 csv = cs[g++]; ry_gate(a0, a1, (w), lane, csv.x, csv.y); }
#define CNG(c, t) cnot_gate(a0, a1, (c), (t), lane);

#pragma unroll
  for (int j = 0; j < 6; ++j) {
    int sq = 7 - j;
    int step = qcstep[j];
    for (int i = 0; i < sq; ++i) { RYG(i); }
    for (int i = 0; i < sq; ++i) {
      if (i == 0) { RYG(0); CNG(sq - 1, 0); RYG(0); }
      else { int w = sq - i; RYG(w); CNG(w - 1, w); RYG(w); }
    }
    for (int i = 0; i < sq; ++i) { RYG(i); }
    int control = 0, controled = step;
    for (int i = 0; i < sq; ++i) {
      RYG(controled); CNG(control, controled); RYG(controled);
      control = controled; controled = (controled + step) % sq;
    }
    for (int i = 0; i < sq - 1; ++i) { RYG(i + 1); CNG(i, i + 1); RYG(i + 1); }
  }
  RYG(0);  // final QF rotation (index 204)

  // scatter to fragment order
  {
    int ks = k >> 5, khi = (k >> 3) & 3, j = k & 7;
    int nf0 = lane >> 4, lr = lane & 15;
    wt[(ks * 8 + nf0) * 512 + khi * 128 + lr * 8 + j] = (_Float16)a0;       // n = lane
    wt[(ks * 8 + nf0 + 4) * 512 + khi * 128 + lr * 8 + j] = (_Float16)a1;   // n = lane+64
  }
#undef RYG
#undef CNG
}

// ---------------- kernel 2: Z = X * U^T, out = row-half prob ----------------
// mfma_f32_16x16x32_f16: A lane l holds A[l&15][(l>>4)*8 + j]
//                        B lane l holds B[(l>>4)*8 + j][l&15]
//                        D lane l holds D[(l>>4)*4 + r][l&15]
// W is staged linearly in LDS in fragment order: the (ks,nf) B-fragment read
// is `lds + (ks*8+nf)*1024 + lane*16` — consecutive 16 B per lane, zero bank
// conflicts, one base reg + immediate offsets.
__global__ __launch_bounds__(256, 4) void qcnn_gemm(
    const float* __restrict__ X, const _Float16* __restrict__ wt,
    float* __restrict__ out, int M) {
  __shared__ uint4 ldsbuf[2048];  // 32 KB: W in fragment order
  int tid = threadIdx.x;
  int wave = tid >> 6, lane = tid & 63;
  int lr = lane & 15;
  int g = lane >> 4;
  int lk = g * 8;

  size_t base0 = (size_t)blockIdx.x * 256 + wave * 16;  // this wave's row base

  // prefetch iter-0 X loads (in flight during LDS staging + barrier)
  float4 v0[4], v1[4];
  if (base0 < (size_t)M) {
    const float* xp = X + (base0 + lr) * 128 + lk;
#pragma unroll
    for (int ks = 0; ks < 4; ++ks) {
      v0[ks] = *(const float4*)(xp + ks * 32);
      v1[ks] = *(const float4*)(xp + ks * 32 + 4);
    }
  }

  // stage W -> LDS: straight linear copy, fully coalesced
  {
    const uint4* wv = (const uint4*)wt;
#pragma unroll
    for (int c = 0; c < 8; ++c) ldsbuf[c * 256 + tid] = wv[c * 256 + tid];
  }
  __syncthreads();

  const char* bbase = (const char*)ldsbuf + lane * 16;

#pragma unroll
  for (int t = 0; t < 4; ++t) {
    size_t rb = base0 + (size_t)t * 64;
    if (rb < (size_t)M) {
      // convert current tile to f16 A-fragments (frees v0/v1)
      f16x8 a[4];
#pragma unroll
      for (int ks = 0; ks < 4; ++ks) {
        auto p0 = __builtin_amdgcn_cvt_pkrtz(v0[ks].x, v0[ks].y);
        auto p1 = __builtin_amdgcn_cvt_pkrtz(v0[ks].z, v0[ks].w);
        auto p2 = __builtin_amdgcn_cvt_pkrtz(v1[ks].x, v1[ks].y);
        auto p3 = __builtin_amdgcn_cvt_pkrtz(v1[ks].z, v1[ks].w);
        f16x8 f;
        f[0] = (_Float16)p0[0]; f[1] = (_Float16)p0[1];
        f[2] = (_Float16)p1[0]; f[3] = (_Float16)p1[1];
        f[4] = (_Float16)p2[0]; f[5] = (_Float16)p2[1];
        f[6] = (_Float16)p3[0]; f[7] = (_Float16)p3[1];
        a[ks] = f;
      }

      // issue next tile's loads early — in flight during MFMA + epilogue
      if (t < 3) {
        size_t rn = base0 + (size_t)(t + 1) * 64;
        if (rn < (size_t)M) {
          const float* xp = X + (rn + lr) * 128 + lk;
#pragma unroll
          for (int ks = 0; ks < 4; ++ks) {
            v0[ks] = *(const float4*)(xp + ks * 32);
            v1[ks] = *(const float4*)(xp + ks * 32 + 4);
          }
        }
      }

      f32x4 acc[8];
#pragma unroll
      for (int nf = 0; nf < 8; ++nf) acc[nf] = (f32x4){0.f, 0.f, 0.f, 0.f};

#pragma unroll
      for (int ks = 0; ks < 4; ++ks) {
#pragma unroll
        for (int nf = 0; nf < 8; ++nf) {
          f16x8 b = *(const f16x8*)(bbase + (ks * 8 + nf) * 1024);
          acc[nf] = __builtin_amdgcn_mfma_f32_16x16x32_f16(a[ks], b, acc[nf], 0, 0, 0);
        }
      }

      // epilogue: s0 = sum_{n<64} z^2, s1 = sum_{n>=64} z^2 per row
      float s0[4], s1[4];
#pragma unroll
      for (int r = 0; r < 4; ++r) {
        float t0 = 0.f, t1 = 0.f;
#pragma unroll
        for (int nf = 0; nf < 4; ++nf) t0 += acc[nf][r] * acc[nf][r];
#pragma unroll
        for (int nf = 4; nf < 8; ++nf) t1 += acc[nf][r] * acc[nf][r];
        s0[r] = t0; s1[r] = t1;
      }
#pragma unroll
      for (int d = 1; d < 16; d <<= 1) {  // reduce across the 16-lane group
#pragma unroll
        for (int r = 0; r < 4; ++r) {
          s0[r] += __shfl_xor(s0[r], d);
          s1[r] += __shfl_xor(s1[r], d);
        }
      }
      size_t row = rb + g * 4;
#pragma unroll
      for (int r = 0; r < 4; ++r) {
        if ((lane & 15) == r) {
          float inv = 1.0f / (s0[r] + s1[r]);
          *(float2*)(out + (row + r) * 2) =
              make_float2(s0[r] * inv, s1[r] * inv);
        }
      }
    }
  }
}

// ---------------------------------------------------------------------------
extern "C" void kernel_launch(void* const* d_in, const int* in_sizes, int n_in,
                              void* d_out, int out_size, void* d_ws,
                              size_t ws_size, hipStream_t stream) {
  const float* X = (const float*)d_in[0];
  _Float16* wt = (_Float16*)d_ws;  // 128*128 f16 = 32 KB, fragment order

  // setup_inputs() dict order is INTERLEAVED: x, QC1, QP1, QC2, QP2, ...,
  // QC6, QP6, QF  (QC{j+1} and QP{j+1} inserted in the same loop iteration).
  basis_kernel<<<128, 64, 0, stream>>>(
      /*qc1*/ (const float*)d_in[1], /*qc2*/ (const float*)d_in[3],
      /*qc3*/ (const float*)d_in[5], /*qc4*/ (const float*)d_in[7],
      /*qc5*/ (const float*)d_in[9], /*qc6*/ (const float*)d_in[11],
      /*qp1*/ (const float*)d_in[2], /*qp2*/ (const float*)d_in[4],
      /*qp3*/ (const float*)d_in[6], /*qp4*/ (const float*)d_in[8],
      /*qp5*/ (const float*)d_in[10], /*qp6*/ (const float*)d_in[12],
      /*qf*/ (const float*)d_in[13], wt);

  int M = in_sizes[0] / 128;  // 262144
  int nblk = (M + 255) / 256;
  qcnn_gemm<<<nblk, 256, 0, stream>>>(X, wt, (float*)d_out, M);
}